// Round 1
// baseline (8626.009 us; speedup 1.0000x reference)
//
#include <hip/hip_runtime.h>
#include <math.h>

// Problem constants (shapes fixed by the harness; a few derived at launch).
constexpr int NB  = 64;    // batch
constexpr int NH  = 512;   // hidden
constexpr int NH3 = 1536;  // 3*hidden
constexpr int BOSTOK = 2;

__device__ __forceinline__ float sigmoidf_(float x) { return 1.0f / (1.0f + expf(-x)); }

// ---------------------------------------------------------------------------
// init: zero h0 (encoder initial hidden), set e_T to emb_dec[BOS] for all b.
// e_T layout: [k][b]  (k-major, lanes over b -> coalesced reads later)
__global__ __launch_bounds__(256) void k_init(float* __restrict__ h0,
                                              float* __restrict__ eT,
                                              const float* __restrict__ emb_dec) {
    int i = blockIdx.x * 256 + threadIdx.x;  // grid covers NH*NB = 32768
    if (i < NH * NB) {
        h0[i] = 0.0f;
        eT[i] = emb_dec[BOSTOK * NH + (i >> 6)];  // row BOS, element k = i/64
    }
}

// ---------------------------------------------------------------------------
// Gather + transpose encoder embeddings: x_T[t][k][b] = emb_enc[tok[t][b]][k]
__global__ __launch_bounds__(256) void k_xgather(const int* __restrict__ tokens,  // (T,B)
                                                 const float* __restrict__ emb,   // (V_IN,H)
                                                 float* __restrict__ xT) {
    const int t = blockIdx.x;
    const int b = threadIdx.x & 63;
    const int kk = threadIdx.x >> 6;
    const int row = tokens[t * NB + b];
    const float* __restrict__ er = emb + (size_t)row * NH;
    float* __restrict__ xo = xT + (size_t)t * NH * NB;
    for (int k = kk; k < NH; k += 4)
        xo[k * NB + b] = er[k];  // write coalesced over b
}

// ---------------------------------------------------------------------------
// Precompute encoder input gates for ALL timesteps:
// gi[t][g*H + j][b] = x_t[b] . Wih_e[g*H+j] + bih_e[g*H+j]
// grid: (H/4, T), block 256 = 64 b-lanes x 4 jj
__global__ __launch_bounds__(256) void k_gi(const float* __restrict__ xT,
                                            const float* __restrict__ Wih,
                                            const float* __restrict__ bih,
                                            float* __restrict__ gi) {
    const int t = blockIdx.y;
    const int tid = threadIdx.x;
    const int b = tid & 63;
    const int jj = tid >> 6;
    const int j = blockIdx.x * 4 + jj;
    const float* __restrict__ x  = xT + (size_t)t * NH * NB;
    const float* __restrict__ wr = Wih + (size_t)j * NH;
    const float* __restrict__ wz = Wih + (size_t)(NH + j) * NH;
    const float* __restrict__ wn = Wih + (size_t)(2 * NH + j) * NH;
    float ar = 0.f, az = 0.f, an = 0.f;
#pragma unroll 4
    for (int k = 0; k < NH; k += 4) {
        const float4 r4 = *(const float4*)(wr + k);
        const float4 z4 = *(const float4*)(wz + k);
        const float4 n4 = *(const float4*)(wn + k);
        const float x0 = x[(k + 0) * NB + b];
        const float x1 = x[(k + 1) * NB + b];
        const float x2 = x[(k + 2) * NB + b];
        const float x3 = x[(k + 3) * NB + b];
        ar += r4.x * x0 + r4.y * x1 + r4.z * x2 + r4.w * x3;
        az += z4.x * x0 + z4.y * x1 + z4.z * x2 + z4.w * x3;
        an += n4.x * x0 + n4.y * x1 + n4.z * x2 + n4.w * x3;
    }
    float* __restrict__ go = gi + (size_t)t * NH3 * NB;
    go[j * NB + b]            = ar + bih[j];
    go[(NH + j) * NB + b]     = az + bih[NH + j];
    go[(2 * NH + j) * NB + b] = an + bih[2 * NH + j];
}

// ---------------------------------------------------------------------------
// One encoder GRU step. h layouts are k-major [k][b]. Packed-seq freeze via mask.
// grid: H/4 = 128 blocks, block 256 = 64 b x 4 jj
__global__ __launch_bounds__(256) void k_enc_step(const float* __restrict__ hc,
                                                  float* __restrict__ hn,
                                                  const float* __restrict__ gi_t,
                                                  const float* __restrict__ Whh,
                                                  const float* __restrict__ bhh,
                                                  const int* __restrict__ lengths,
                                                  int t) {
    const int tid = threadIdx.x;
    const int b = tid & 63;
    const int jj = tid >> 6;
    const int j = blockIdx.x * 4 + jj;
    const float* __restrict__ wr = Whh + (size_t)j * NH;
    const float* __restrict__ wz = Whh + (size_t)(NH + j) * NH;
    const float* __restrict__ wn = Whh + (size_t)(2 * NH + j) * NH;
    float ar = 0.f, az = 0.f, an = 0.f;
#pragma unroll 4
    for (int k = 0; k < NH; k += 4) {
        const float4 r4 = *(const float4*)(wr + k);
        const float4 z4 = *(const float4*)(wz + k);
        const float4 n4 = *(const float4*)(wn + k);
        const float h0 = hc[(k + 0) * NB + b];
        const float h1 = hc[(k + 1) * NB + b];
        const float h2 = hc[(k + 2) * NB + b];
        const float h3 = hc[(k + 3) * NB + b];
        ar += r4.x * h0 + r4.y * h1 + r4.z * h2 + r4.w * h3;
        az += z4.x * h0 + z4.y * h1 + z4.z * h2 + z4.w * h3;
        an += n4.x * h0 + n4.y * h1 + n4.z * h2 + n4.w * h3;
    }
    const float hj = hc[j * NB + b];
    const float r = sigmoidf_(gi_t[j * NB + b] + ar + bhh[j]);
    const float z = sigmoidf_(gi_t[(NH + j) * NB + b] + az + bhh[NH + j]);
    const float n = tanhf(gi_t[(2 * NH + j) * NB + b] + r * (an + bhh[2 * NH + j]));
    const float hv = (1.f - z) * n + z * hj;
    hn[j * NB + b] = (t < lengths[b]) ? hv : hj;  // freeze after sequence end
}

// ---------------------------------------------------------------------------
// One decoder GRU step: gi computed on the fly from e_T; writes h in BOTH
// layouts (k-major h_T for next GRU, b-major h_lin for the logits kernel).
__global__ __launch_bounds__(256) void k_dec_gru(const float* __restrict__ hc,
                                                 float* __restrict__ hn,
                                                 float* __restrict__ hlin,
                                                 const float* __restrict__ eT,
                                                 const float* __restrict__ Wih,
                                                 const float* __restrict__ Whh,
                                                 const float* __restrict__ bih,
                                                 const float* __restrict__ bhh) {
    const int tid = threadIdx.x;
    const int b = tid & 63;
    const int jj = tid >> 6;
    const int j = blockIdx.x * 4 + jj;
    const float* __restrict__ ir_w = Wih + (size_t)j * NH;
    const float* __restrict__ iz_w = Wih + (size_t)(NH + j) * NH;
    const float* __restrict__ in_w = Wih + (size_t)(2 * NH + j) * NH;
    const float* __restrict__ hr_w = Whh + (size_t)j * NH;
    const float* __restrict__ hz_w = Whh + (size_t)(NH + j) * NH;
    const float* __restrict__ hn_w = Whh + (size_t)(2 * NH + j) * NH;
    float air = 0.f, aiz = 0.f, ain = 0.f;
    float ahr = 0.f, ahz = 0.f, ahn = 0.f;
#pragma unroll 2
    for (int k = 0; k < NH; k += 4) {
        const float4 a4 = *(const float4*)(ir_w + k);
        const float4 b4 = *(const float4*)(iz_w + k);
        const float4 c4 = *(const float4*)(in_w + k);
        const float4 d4 = *(const float4*)(hr_w + k);
        const float4 e4 = *(const float4*)(hz_w + k);
        const float4 f4 = *(const float4*)(hn_w + k);
        const float e0 = eT[(k + 0) * NB + b];
        const float e1 = eT[(k + 1) * NB + b];
        const float e2 = eT[(k + 2) * NB + b];
        const float e3 = eT[(k + 3) * NB + b];
        const float h0 = hc[(k + 0) * NB + b];
        const float h1 = hc[(k + 1) * NB + b];
        const float h2 = hc[(k + 2) * NB + b];
        const float h3 = hc[(k + 3) * NB + b];
        air += a4.x * e0 + a4.y * e1 + a4.z * e2 + a4.w * e3;
        aiz += b4.x * e0 + b4.y * e1 + b4.z * e2 + b4.w * e3;
        ain += c4.x * e0 + c4.y * e1 + c4.z * e2 + c4.w * e3;
        ahr += d4.x * h0 + d4.y * h1 + d4.z * h2 + d4.w * h3;
        ahz += e4.x * h0 + e4.y * h1 + e4.z * h2 + e4.w * h3;
        ahn += f4.x * h0 + f4.y * h1 + f4.z * h2 + f4.w * h3;
    }
    const float hj = hc[j * NB + b];
    const float r = sigmoidf_(air + bih[j] + ahr + bhh[j]);
    const float z = sigmoidf_(aiz + bih[NH + j] + ahz + bhh[NH + j]);
    const float n = tanhf(ain + bih[2 * NH + j] + r * (ahn + bhh[2 * NH + j]));
    const float hv = (1.f - z) * n + z * hj;
    hn[j * NB + b] = hv;
    hlin[(size_t)b * NH + j] = hv;
}

// ---------------------------------------------------------------------------
// Decoder logits: out_t[b][v] = h[b] . Wout[v] + bout[v]
// grid (V/128, 2); block 256 = 64 v-lanes x 4 bu; v-tile 128, b-tile 32.
// h-slab (32 rows, 64 KB) staged in LDS -> broadcast ds_read_b128 in k-loop.
__global__ __launch_bounds__(256) void k_dec_logits(const float* __restrict__ hlin,
                                                    const float* __restrict__ Wout,
                                                    const float* __restrict__ bout,
                                                    float* __restrict__ outp,
                                                    int V) {
    __shared__ __align__(16) float hsh[32 * NH];  // 64 KB
    const int tid = threadIdx.x;
    const int bg = blockIdx.y;
    {   // stage 32 h rows, coalesced float4
        const float4* __restrict__ src = (const float4*)(hlin + (size_t)bg * 32 * NH);
        float4* __restrict__ dst = (float4*)hsh;
        for (int i = tid; i < 32 * NH / 4; i += 256) dst[i] = src[i];
    }
    __syncthreads();
    const int vlane = tid & 63;
    const int bu = tid >> 6;
    const int v0 = blockIdx.x * 128 + vlane;
    const int v1 = v0 + 64;
    const float* __restrict__ w0 = Wout + (size_t)v0 * NH;
    const float* __restrict__ w1 = Wout + (size_t)v1 * NH;
    float acc0[8], acc1[8];
#pragma unroll
    for (int w = 0; w < 8; ++w) { acc0[w] = 0.f; acc1[w] = 0.f; }
    for (int k = 0; k < NH; k += 4) {
        const float4 a = *(const float4*)(w0 + k);
        const float4 c = *(const float4*)(w1 + k);
#pragma unroll
        for (int w = 0; w < 8; ++w) {
            const float4 h4 = *(const float4*)(&hsh[(bu * 8 + w) * NH + k]);  // broadcast
            acc0[w] += a.x * h4.x + a.y * h4.y + a.z * h4.z + a.w * h4.w;
            acc1[w] += c.x * h4.x + c.y * h4.y + c.z * h4.z + c.w * h4.w;
        }
    }
    const float b0 = bout[v0];
    const float b1 = bout[v1];
#pragma unroll
    for (int w = 0; w < 8; ++w) {
        const int b = bg * 32 + bu * 8 + w;
        outp[(size_t)b * V + v0] = acc0[w] + b0;
        outp[(size_t)b * V + v1] = acc1[w] + b1;
    }
}

// ---------------------------------------------------------------------------
// Per-batch argmax over V logits (np semantics: FIRST max index wins),
// fused with the embedding gather for the next decoder input.
__global__ __launch_bounds__(256) void k_argmax_embed(const float* __restrict__ logits_t,  // (B,V)
                                                      const float* __restrict__ emb_dec,
                                                      float* __restrict__ eT,
                                                      int V) {
    const int b = blockIdx.x;
    const int tid = threadIdx.x;
    const float* __restrict__ lp = logits_t + (size_t)b * V;
    float best = -INFINITY;
    int bi = 0x7fffffff;
    for (int v = tid; v < V; v += 256) {   // per-thread v strictly increasing -> '>' keeps first
        const float x = lp[v];
        if (x > best) { best = x; bi = v; }
    }
    __shared__ float sv[256];
    __shared__ int si[256];
    sv[tid] = best;
    si[tid] = bi;
    __syncthreads();
    for (int s = 128; s > 0; s >>= 1) {
        if (tid < s) {
            const float ov = sv[tid + s];
            const int oi = si[tid + s];
            if (ov > sv[tid] || (ov == sv[tid] && oi < si[tid])) { sv[tid] = ov; si[tid] = oi; }
        }
        __syncthreads();
    }
    const int tok = si[0];
    const float* __restrict__ er = emb_dec + (size_t)tok * NH;
    for (int k = tid; k < NH; k += 256)
        eT[k * NB + b] = er[k];
}

// ---------------------------------------------------------------------------
extern "C" void kernel_launch(void* const* d_in, const int* in_sizes, int n_in,
                              void* d_out, int out_size, void* d_ws, size_t ws_size,
                              hipStream_t stream) {
    const int*   batch_X = (const int*)d_in[0];
    const int*   lengths = (const int*)d_in[1];
    // d_in[2] = max_length (device scalar) -- derived from out_size instead
    const float* emb_enc = (const float*)d_in[3];
    const float* Wih_e   = (const float*)d_in[4];
    const float* Whh_e   = (const float*)d_in[5];
    const float* bih_e   = (const float*)d_in[6];
    const float* bhh_e   = (const float*)d_in[7];
    const float* emb_dec = (const float*)d_in[8];
    const float* Wih_d   = (const float*)d_in[9];
    const float* Whh_d   = (const float*)d_in[10];
    const float* bih_d   = (const float*)d_in[11];
    const float* bhh_d   = (const float*)d_in[12];
    const float* Wout    = (const float*)d_in[13];
    const float* bout    = (const float*)d_in[14];

    const int T = in_sizes[0] / NB;            // 128
    const int V = in_sizes[14];                // 32000 (bout size)
    const int STEPS = out_size / (NB * V);     // 32

    float* out = (float*)d_out;

    // Small persistent scratch in d_ws (512 KB): h ping-pong + h_lin + e_T.
    float* h0   = (float*)d_ws;
    float* h1   = h0 + NH * NB;
    float* hlin = h1 + NH * NB;
    float* eT   = hlin + NH * NB;

    // Big encoder-phase scratch carved from the TAIL of d_out: the decoder
    // only overwrites this region from step ~23 on, long after encoder done.
    const size_t xT_off = (size_t)out_size - (size_t)T * NH * NB;       // 4.19M floats
    const size_t gi_off = xT_off - (size_t)T * NH3 * NB;                // 12.58M floats
    float* xT = out + xT_off;
    float* gi = out + gi_off;

    k_init<<<dim3((NH * NB + 255) / 256), dim3(256), 0, stream>>>(h0, eT, emb_dec);
    k_xgather<<<dim3(T), dim3(256), 0, stream>>>(batch_X, emb_enc, xT);
    k_gi<<<dim3(NH / 4, T), dim3(256), 0, stream>>>(xT, Wih_e, bih_e, gi);

    float* hc = h0;
    float* hn = h1;
    for (int t = 0; t < T; ++t) {
        k_enc_step<<<dim3(NH / 4), dim3(256), 0, stream>>>(
            hc, hn, gi + (size_t)t * NH3 * NB, Whh_e, bhh_e, lengths, t);
        float* tmp = hc; hc = hn; hn = tmp;
    }
    // hc now holds the final encoder hidden state.
    for (int s = 0; s < STEPS; ++s) {
        k_dec_gru<<<dim3(NH / 4), dim3(256), 0, stream>>>(
            hc, hn, hlin, eT, Wih_d, Whh_d, bih_d, bhh_d);
        { float* tmp = hc; hc = hn; hn = tmp; }
        float* out_t = out + (size_t)s * NB * V;
        k_dec_logits<<<dim3(V / 128, 2), dim3(256), 0, stream>>>(hlin, Wout, bout, out_t, V);
        if (s + 1 < STEPS)
            k_argmax_embed<<<dim3(NB), dim3(256), 0, stream>>>(out_t, emb_dec, eT, V);
    }
}

// Round 2
// 8224.065 us; speedup vs baseline: 1.0489x; 1.0489x over previous
//
#include <hip/hip_runtime.h>
#include <math.h>

// Shapes fixed by the problem.
constexpr int NB  = 64;    // batch
constexpr int NH  = 512;   // hidden
constexpr int BOSTOK = 2;

__device__ __forceinline__ float sigmoidf_(float x) { return 1.0f / (1.0f + expf(-x)); }

// ---------------------------------------------------------------------------
// init: zero hA (encoder h0, quad layout), set e_T to emb_dec[BOS], zero barrier.
__global__ __launch_bounds__(256) void k_init(float* __restrict__ hA,
                                              float* __restrict__ eT,
                                              const float* __restrict__ emb_dec,
                                              int* __restrict__ bar) {
    int i = blockIdx.x * 256 + threadIdx.x;  // covers NH*NB = 32768
    if (i < NH * NB) {
        hA[i] = 0.0f;
        eT[i] = emb_dec[BOSTOK * NH + (i >> 6)];
    }
    if (i == 0) *bar = 0;
}

// ---------------------------------------------------------------------------
// Gather encoder embeddings into quad-packed layout:
// xT4[t][kq][b][c] = emb_enc[tok[t][b]][4*kq + c]   (kq in [0,128))
__global__ __launch_bounds__(256) void k_xgather(const int* __restrict__ tokens,  // (T,B)
                                                 const float* __restrict__ emb,   // (V_IN,H)
                                                 float* __restrict__ xT4) {
    const int t = blockIdx.x;
    const int b = threadIdx.x & 63;
    const int kk = threadIdx.x >> 6;  // 0..3
    const int row = tokens[t * NB + b];
    const float* __restrict__ er = emb + (size_t)row * NH;
    float* __restrict__ xo = xT4 + (size_t)t * NH * NB;
    for (int kq = kk; kq < NH / 4; kq += 4) {
        const float4 e4 = *(const float4*)(er + kq * 4);
        *(float4*)(xo + kq * 256 + b * 4) = e4;   // coalesced: lane b -> 16B slot
    }
}

// ---------------------------------------------------------------------------
// PERSISTENT ENCODER: all T GRU steps in one launch.
// Grid: 256 blocks x 256 threads (1 block/CU, co-resident). Block owns 2 j's.
// Wave = (j, K-half): lanes<->b; weight quads are wave-uniform (scalar loads),
// x/h quads are coalesced float4. gi (Wih@x_t) computed inline each step.
// h quad layout: h[kq*256 + b*4 + c] = h_elem[4kq+c][b].
// Cross-block h exchange via device-scope barrier (release wb / acquire inv).
__global__ __launch_bounds__(256, 1) void k_enc_persist(
        const float* __restrict__ xT4,
        const float* __restrict__ Wih, const float* __restrict__ Whh,
        const float* __restrict__ bih, const float* __restrict__ bhh,
        const int* __restrict__ lengths,
        float* __restrict__ hA, float* __restrict__ hB,
        float* __restrict__ hfin,          // plain k-major [j*64+b] for decoder
        int* __restrict__ bar, int T) {
    __shared__ float red[2 * 6 * 64];      // kh=1 partials: [jj][6][64]

    const int tid  = threadIdx.x;
    const int lane = tid & 63;                                    // b
    const int wv   = __builtin_amdgcn_readfirstlane(tid >> 6);    // 0..3, scalar
    const int jj   = wv >> 1;                                     // j within block
    const int kh   = wv & 1;                                      // K-half
    const int j    = blockIdx.x * 2 + jj;                         // 0..511
    const int kqb  = kh * (NH / 8);                               // base quad (0 or 64)

    // Wave-uniform (scalar) row pointers, offset to this wave's K-half.
    const float* __restrict__ wir = Wih + (size_t)j * NH            + kqb * 4;
    const float* __restrict__ wiz = Wih + (size_t)(NH + j) * NH     + kqb * 4;
    const float* __restrict__ win = Wih + (size_t)(2 * NH + j) * NH + kqb * 4;
    const float* __restrict__ whr = Whh + (size_t)j * NH            + kqb * 4;
    const float* __restrict__ whz = Whh + (size_t)(NH + j) * NH     + kqb * 4;
    const float* __restrict__ whn = Whh + (size_t)(2 * NH + j) * NH + kqb * 4;

    const float bir = bih[j], biz = bih[NH + j], bin_ = bih[2 * NH + j];
    const float bhr = bhh[j], bhz = bhh[NH + j], bhn  = bhh[2 * NH + j];
    const int   len = lengths[lane];
    const int nblk = gridDim.x;

    for (int t = 0; t < T; ++t) {
        const float* __restrict__ hc = (t & 1) ? hB : hA;
        float*       __restrict__ hn = (t & 1) ? hA : hB;
        const float* __restrict__ xt = xT4 + (size_t)t * NH * NB;

        float a_ir = 0.f, a_iz = 0.f, a_in = 0.f;
        float a_hr = 0.f, a_hz = 0.f, a_hn = 0.f;
#pragma unroll 4
        for (int kq = 0; kq < NH / 8; ++kq) {
            const int kg = kqb + kq;
            const float4 xq = *(const float4*)(xt + kg * 256 + lane * 4);
            const float4 hq = *(const float4*)(hc + kg * 256 + lane * 4);
            const float4 w0 = *(const float4*)(wir + kq * 4);   // scalar s_load
            const float4 w1 = *(const float4*)(wiz + kq * 4);
            const float4 w2 = *(const float4*)(win + kq * 4);
            const float4 w3 = *(const float4*)(whr + kq * 4);
            const float4 w4 = *(const float4*)(whz + kq * 4);
            const float4 w5 = *(const float4*)(whn + kq * 4);
            a_ir += w0.x * xq.x + w0.y * xq.y + w0.z * xq.z + w0.w * xq.w;
            a_iz += w1.x * xq.x + w1.y * xq.y + w1.z * xq.z + w1.w * xq.w;
            a_in += w2.x * xq.x + w2.y * xq.y + w2.z * xq.z + w2.w * xq.w;
            a_hr += w3.x * hq.x + w3.y * hq.y + w3.z * hq.z + w3.w * hq.w;
            a_hz += w4.x * hq.x + w4.y * hq.y + w4.z * hq.z + w4.w * hq.w;
            a_hn += w5.x * hq.x + w5.y * hq.y + w5.z * hq.z + w5.w * hq.w;
        }

        // Combine the two K-halves of each j within the block.
        if (kh == 1) {
            float* s = red + jj * 384 + lane;
            s[0] = a_ir; s[64] = a_iz; s[128] = a_in;
            s[192] = a_hr; s[256] = a_hz; s[320] = a_hn;
        }
        __syncthreads();
        if (kh == 0) {
            const float* s = red + jj * 384 + lane;
            a_ir += s[0];  a_iz += s[64];  a_in += s[128];
            a_hr += s[192]; a_hz += s[256]; a_hn += s[320];
            const float r = sigmoidf_(a_ir + bir + a_hr + bhr);
            const float z = sigmoidf_(a_iz + biz + a_hz + bhz);
            const float n = tanhf(a_in + bin_ + r * (a_hn + bhn));
            const int qoff = (j >> 2) * 256 + lane * 4 + (j & 3);
            const float hold = hc[qoff];
            const float hv = (t < len) ? ((1.f - z) * n + z * hold) : hold;
            hn[qoff] = hv;
            if (t == T - 1) hfin[j * NB + lane] = hv;
        }
        // Device-wide barrier: release(writeback L2) on arrive, acquire(inv) on spin.
        __syncthreads();   // drains this block's stores (vmcnt 0) before arrive
        if (tid == 0) {
            __hip_atomic_fetch_add(bar, 1, __ATOMIC_RELEASE, __HIP_MEMORY_SCOPE_AGENT);
            const int tgt = nblk * (t + 1);
            while (__hip_atomic_load(bar, __ATOMIC_ACQUIRE, __HIP_MEMORY_SCOPE_AGENT) < tgt)
                __builtin_amdgcn_s_sleep(4);
        }
        __syncthreads();
    }
}

// ---------------------------------------------------------------------------
// One decoder GRU step (unchanged from round 1): gi on the fly from e_T;
// writes h in k-major h_T (next GRU) and b-major h_lin (logits kernel).
__global__ __launch_bounds__(256) void k_dec_gru(const float* __restrict__ hc,
                                                 float* __restrict__ hn,
                                                 float* __restrict__ hlin,
                                                 const float* __restrict__ eT,
                                                 const float* __restrict__ Wih,
                                                 const float* __restrict__ Whh,
                                                 const float* __restrict__ bih,
                                                 const float* __restrict__ bhh) {
    const int tid = threadIdx.x;
    const int b = tid & 63;
    const int jj = tid >> 6;
    const int j = blockIdx.x * 4 + jj;
    const float* __restrict__ ir_w = Wih + (size_t)j * NH;
    const float* __restrict__ iz_w = Wih + (size_t)(NH + j) * NH;
    const float* __restrict__ in_w = Wih + (size_t)(2 * NH + j) * NH;
    const float* __restrict__ hr_w = Whh + (size_t)j * NH;
    const float* __restrict__ hz_w = Whh + (size_t)(NH + j) * NH;
    const float* __restrict__ hn_w = Whh + (size_t)(2 * NH + j) * NH;
    float air = 0.f, aiz = 0.f, ain = 0.f;
    float ahr = 0.f, ahz = 0.f, ahn = 0.f;
#pragma unroll 2
    for (int k = 0; k < NH; k += 4) {
        const float4 a4 = *(const float4*)(ir_w + k);
        const float4 b4 = *(const float4*)(iz_w + k);
        const float4 c4 = *(const float4*)(in_w + k);
        const float4 d4 = *(const float4*)(hr_w + k);
        const float4 e4 = *(const float4*)(hz_w + k);
        const float4 f4 = *(const float4*)(hn_w + k);
        const float e0 = eT[(k + 0) * NB + b];
        const float e1 = eT[(k + 1) * NB + b];
        const float e2 = eT[(k + 2) * NB + b];
        const float e3 = eT[(k + 3) * NB + b];
        const float h0 = hc[(k + 0) * NB + b];
        const float h1 = hc[(k + 1) * NB + b];
        const float h2 = hc[(k + 2) * NB + b];
        const float h3 = hc[(k + 3) * NB + b];
        air += a4.x * e0 + a4.y * e1 + a4.z * e2 + a4.w * e3;
        aiz += b4.x * e0 + b4.y * e1 + b4.z * e2 + b4.w * e3;
        ain += c4.x * e0 + c4.y * e1 + c4.z * e2 + c4.w * e3;
        ahr += d4.x * h0 + d4.y * h1 + d4.z * h2 + d4.w * h3;
        ahz += e4.x * h0 + e4.y * h1 + e4.z * h2 + e4.w * h3;
        ahn += f4.x * h0 + f4.y * h1 + f4.z * h2 + f4.w * h3;
    }
    const float hj = hc[j * NB + b];
    const float r = sigmoidf_(air + bih[j] + ahr + bhh[j]);
    const float z = sigmoidf_(aiz + bih[NH + j] + ahz + bhh[NH + j]);
    const float n = tanhf(ain + bih[2 * NH + j] + r * (ahn + bhh[2 * NH + j]));
    const float hv = (1.f - z) * n + z * hj;
    hn[j * NB + b] = hv;
    hlin[(size_t)b * NH + j] = hv;
}

// ---------------------------------------------------------------------------
// Decoder logits (unchanged): out_t[b][v] = h[b].Wout[v] + bout[v]
__global__ __launch_bounds__(256) void k_dec_logits(const float* __restrict__ hlin,
                                                    const float* __restrict__ Wout,
                                                    const float* __restrict__ bout,
                                                    float* __restrict__ outp,
                                                    int V) {
    __shared__ __align__(16) float hsh[32 * NH];  // 64 KB
    const int tid = threadIdx.x;
    const int bg = blockIdx.y;
    {
        const float4* __restrict__ src = (const float4*)(hlin + (size_t)bg * 32 * NH);
        float4* __restrict__ dst = (float4*)hsh;
        for (int i = tid; i < 32 * NH / 4; i += 256) dst[i] = src[i];
    }
    __syncthreads();
    const int vlane = tid & 63;
    const int bu = tid >> 6;
    const int v0 = blockIdx.x * 128 + vlane;
    const int v1 = v0 + 64;
    const float* __restrict__ w0 = Wout + (size_t)v0 * NH;
    const float* __restrict__ w1 = Wout + (size_t)v1 * NH;
    float acc0[8], acc1[8];
#pragma unroll
    for (int w = 0; w < 8; ++w) { acc0[w] = 0.f; acc1[w] = 0.f; }
    for (int k = 0; k < NH; k += 4) {
        const float4 a = *(const float4*)(w0 + k);
        const float4 c = *(const float4*)(w1 + k);
#pragma unroll
        for (int w = 0; w < 8; ++w) {
            const float4 h4 = *(const float4*)(&hsh[(bu * 8 + w) * NH + k]);
            acc0[w] += a.x * h4.x + a.y * h4.y + a.z * h4.z + a.w * h4.w;
            acc1[w] += c.x * h4.x + c.y * h4.y + c.z * h4.z + c.w * h4.w;
        }
    }
    const float b0 = bout[v0];
    const float b1 = bout[v1];
#pragma unroll
    for (int w = 0; w < 8; ++w) {
        const int b = bg * 32 + bu * 8 + w;
        outp[(size_t)b * V + v0] = acc0[w] + b0;
        outp[(size_t)b * V + v1] = acc1[w] + b1;
    }
}

// ---------------------------------------------------------------------------
// Argmax (np first-index tie-break) + next-token embedding gather (unchanged).
__global__ __launch_bounds__(256) void k_argmax_embed(const float* __restrict__ logits_t,
                                                      const float* __restrict__ emb_dec,
                                                      float* __restrict__ eT,
                                                      int V) {
    const int b = blockIdx.x;
    const int tid = threadIdx.x;
    const float* __restrict__ lp = logits_t + (size_t)b * V;
    float best = -INFINITY;
    int bi = 0x7fffffff;
    for (int v = tid; v < V; v += 256) {
        const float x = lp[v];
        if (x > best) { best = x; bi = v; }
    }
    __shared__ float sv[256];
    __shared__ int si[256];
    sv[tid] = best;
    si[tid] = bi;
    __syncthreads();
    for (int s = 128; s > 0; s >>= 1) {
        if (tid < s) {
            const float ov = sv[tid + s];
            const int oi = si[tid + s];
            if (ov > sv[tid] || (ov == sv[tid] && oi < si[tid])) { sv[tid] = ov; si[tid] = oi; }
        }
        __syncthreads();
    }
    const int tok = si[0];
    const float* __restrict__ er = emb_dec + (size_t)tok * NH;
    for (int k = tid; k < NH; k += 256)
        eT[k * NB + b] = er[k];
}

// ---------------------------------------------------------------------------
extern "C" void kernel_launch(void* const* d_in, const int* in_sizes, int n_in,
                              void* d_out, int out_size, void* d_ws, size_t ws_size,
                              hipStream_t stream) {
    const int*   batch_X = (const int*)d_in[0];
    const int*   lengths = (const int*)d_in[1];
    const float* emb_enc = (const float*)d_in[3];
    const float* Wih_e   = (const float*)d_in[4];
    const float* Whh_e   = (const float*)d_in[5];
    const float* bih_e   = (const float*)d_in[6];
    const float* bhh_e   = (const float*)d_in[7];
    const float* emb_dec = (const float*)d_in[8];
    const float* Wih_d   = (const float*)d_in[9];
    const float* Whh_d   = (const float*)d_in[10];
    const float* bih_d   = (const float*)d_in[11];
    const float* bhh_d   = (const float*)d_in[12];
    const float* Wout    = (const float*)d_in[13];
    const float* bout    = (const float*)d_in[14];

    const int T = in_sizes[0] / NB;            // 128
    const int V = in_sizes[14];                // 32000
    const int STEPS = out_size / (NB * V);     // 32

    float* out = (float*)d_out;

    // d_ws (proven >= 512 KB in round 1): decoder h ping-pong + hlin + eT.
    float* dh0  = (float*)d_ws;
    float* dh1  = dh0 + NH * NB;
    float* hlin = dh1 + NH * NB;
    float* eT   = hlin + NH * NB;

    // Encoder-phase scratch in the TAIL of d_out (region belongs to logits
    // steps s>=29, written long after its last use here):
    //   xT4 (T*NH*NB), hA, hB, hfin (NH*NB each), barrier counter.
    const size_t xT4_off = (size_t)out_size - (size_t)T * NH * NB;
    const size_t hA_off  = xT4_off - NH * NB;
    const size_t hB_off  = hA_off - NH * NB;
    const size_t hf_off  = hB_off - NH * NB;
    const size_t bar_off = hf_off - 64;
    float* xT4  = out + xT4_off;
    float* hA   = out + hA_off;
    float* hB   = out + hB_off;
    float* hfin = out + hf_off;
    int*   bar  = (int*)(out + bar_off);

    k_init<<<dim3((NH * NB + 255) / 256), dim3(256), 0, stream>>>(hA, eT, emb_dec, bar);
    k_xgather<<<dim3(T), dim3(256), 0, stream>>>(batch_X, emb_enc, xT4);
    k_enc_persist<<<dim3(NH / 2), dim3(256), 0, stream>>>(
        xT4, Wih_e, Whh_e, bih_e, bhh_e, lengths, hA, hB, hfin, bar, T);

    // Decoder (unchanged structure).
    const float* hc = hfin;
    float* hn = dh0;
    float* other = dh1;
    for (int s = 0; s < STEPS; ++s) {
        k_dec_gru<<<dim3(NH / 4), dim3(256), 0, stream>>>(
            hc, hn, hlin, eT, Wih_d, Whh_d, bih_d, bhh_d);
        hc = hn; hn = other; other = (float*)hc == dh0 ? dh1 : dh0;
        // (simple ping-pong: after first step alternate dh0/dh1)
        if (s == 0) { hn = dh1; other = dh0; }
        float* out_t = out + (size_t)s * NB * V;
        k_dec_logits<<<dim3(V / 128, 2), dim3(256), 0, stream>>>(hlin, Wout, bout, out_t, V);
        if (s + 1 < STEPS)
            k_argmax_embed<<<dim3(NB), dim3(256), 0, stream>>>(out_t, emb_dec, eT, V);
    }
}